// Round 1
// baseline (2068.866 us; speedup 1.0000x reference)
//
#include <hip/hip_runtime.h>
#include <hip/hip_fp16.h>

// MAHGN: 2-layer hetero GAT, fp32 math / fp16 message payload.
// Round 6: eliminate hs materialization entirely. Aggregate raw x per head
// (weights from folded-attention GEMVs), apply Ws AFTER aggregation in a
// fused per-block epilogue GEMM. x stored once per layer as fp16 for the
// scattered gather reads (halves per-edge bytes; shared across edge types).

static constexpr int kNUser = 200000;
static constexpr int kNArt  = 100000;
static constexpr int kNCat  = 500;
static constexpr size_t SZ_U = (size_t)kNUser * 64;
static constexpr size_t SZ_A = (size_t)kNArt * 64;
static constexpr size_t SZ_C = (size_t)kNCat * 64;
static constexpr size_t SZ_X = SZ_U + SZ_A + SZ_C;
static constexpr int CHUNK = 4096;

__device__ __forceinline__ uint32_t packh2(float a, float b) {
  __half2 t = __floats2half2_rn(a, b);
  return *reinterpret_cast<uint32_t*>(&t);
}
__device__ __forceinline__ float2 unpackh2(uint32_t u) {
  __half2 t = *reinterpret_cast<__half2*>(&u);
  return __half22float2(t);
}

// ---------------- fold: vs[k,h] = sum_c W[k][h*16+c]*att[h*16+c] ----------------
// grid 16 = (l*8+t); writes fold[(lt*2+sd)*256 + k*4 + h] for sd=0(src),1(dst)
__global__ void k_fold(const float* __restrict__ Wsrc, const float* __restrict__ Wdst,
                       const float* __restrict__ attS, const float* __restrict__ attD,
                       float* __restrict__ fold)
{
  int lt = blockIdx.x;
  int tid = threadIdx.x;
  int k = tid >> 2, h = tid & 3;
  const float* Ws = Wsrc + (size_t)lt * 4096;
  const float* Wd = Wdst + (size_t)lt * 4096;
  const float* aS = attS + (size_t)lt * 64;
  const float* aD = attD + (size_t)lt * 64;
  float s = 0.f, d = 0.f;
  #pragma unroll
  for (int c = 0; c < 16; ++c) {
    s += Ws[k * 64 + h * 16 + c] * aS[h * 16 + c];
    d += Wd[k * 64 + h * 16 + c] * aD[h * 16 + c];
  }
  fold[((size_t)lt * 2 + 0) * 256 + tid] = s;
  fold[((size_t)lt * 2 + 1) * 256 + tid] = d;
}

// ---------------- k_attn: per node type, all folded GEMVs + fp16 cast ----------------
// thread = node. Computes aout[n*NV*4 + v*4 + h] = x[n] . fold[slots[v]][:,h]
// and xh[n] = fp16(x[n]).
template <int NV>
__global__ __launch_bounds__(256) void k_attn(const float* __restrict__ x,
    uint4* __restrict__ xh, const float* __restrict__ fold,
    int4 sa, int4 sb, float* __restrict__ aout, int Ns)
{
  __shared__ float sV[NV * 256];
  int tid = threadIdx.x;
  const int slots[8] = {sa.x, sa.y, sa.z, sa.w, sb.x, sb.y, sb.z, sb.w};
  #pragma unroll
  for (int v = 0; v < NV; ++v)
    sV[v * 256 + tid] = fold[(size_t)slots[v] * 256 + tid];
  __syncthreads();
  int n = blockIdx.x * 256 + tid;
  if (n >= Ns) return;
  const float4* xp = (const float4*)(x + (size_t)n * 64);
  float4 xr[16];
  #pragma unroll
  for (int q = 0; q < 16; ++q) xr[q] = xp[q];
  // fp16 pack: 64 halves = 8 x uint4
  uint4* dst = xh + (size_t)n * 8;
  #pragma unroll
  for (int q = 0; q < 8; ++q) {
    uint4 u;
    u.x = packh2(xr[2 * q].x, xr[2 * q].y);
    u.y = packh2(xr[2 * q].z, xr[2 * q].w);
    u.z = packh2(xr[2 * q + 1].x, xr[2 * q + 1].y);
    u.w = packh2(xr[2 * q + 1].z, xr[2 * q + 1].w);
    dst[q] = u;
  }
  #pragma unroll
  for (int v = 0; v < NV; ++v) {
    float a0 = 0.f, a1 = 0.f, a2 = 0.f, a3 = 0.f;
    #pragma unroll
    for (int q = 0; q < 16; ++q) {
      const float* xf = &xr[q].x;
      #pragma unroll
      for (int j = 0; j < 4; ++j) {
        int k = q * 4 + j;
        float4 vv = *(const float4*)&sV[v * 256 + k * 4];
        float xk = xf[j];
        a0 += xk * vv.x; a1 += xk * vv.y; a2 += xk * vv.z; a3 += xk * vv.w;
      }
    }
    *(float4*)(aout + (size_t)n * (NV * 4) + v * 4) = make_float4(a0, a1, a2, a3);
  }
}

// ---------------- CSR build: two-level LDS multisplit (unchanged) ----------------

__global__ __launch_bounds__(256) void k_bhist(const int* __restrict__ col, int E,
    int nblk, int nbin, int shift, int* __restrict__ bh)
{
  __shared__ int h[1024];
  int tid = threadIdx.x;
  for (int j = tid; j < nbin; j += 256) h[j] = 0;
  __syncthreads();
  int b = blockIdx.x;
  int lo = b * CHUNK, hi = min(E, lo + CHUNK);
  for (int i = lo + tid; i < hi; i += 256) atomicAdd(&h[col[i] >> shift], 1);
  __syncthreads();
  for (int j = tid; j < nbin; j += 256) bh[j * nblk + b] = h[j];   // bin-major
}

__global__ __launch_bounds__(256) void k_s1(const int* __restrict__ a,
    int* __restrict__ bsum, int n)
{
  __shared__ int tmp[256];
  int t = threadIdx.x;
  int base = blockIdx.x * 4096 + t * 16;
  int s = 0;
  #pragma unroll
  for (int i = 0; i < 16; ++i) { int idx = base + i; if (idx < n) s += a[idx]; }
  tmp[t] = s;
  __syncthreads();
  for (int off = 128; off > 0; off >>= 1) {
    if (t < off) tmp[t] += tmp[t + off];
    __syncthreads();
  }
  if (t == 0) bsum[blockIdx.x] = tmp[0];
}

__global__ __launch_bounds__(1024) void k_s2(int* __restrict__ bsum, int nb) {
  __shared__ int tmp[1024];
  int t = threadIdx.x;
  int v = (t < nb) ? bsum[t] : 0;
  tmp[t] = v;
  __syncthreads();
  for (int off = 1; off < 1024; off <<= 1) {
    int u = (t >= off) ? tmp[t - off] : 0;
    __syncthreads();
    tmp[t] += u;
    __syncthreads();
  }
  if (t < nb) bsum[t] = tmp[t] - v;   // exclusive
}

__global__ __launch_bounds__(256) void k_s3(int* __restrict__ a,
    const int* __restrict__ bsum, int n)
{
  __shared__ int tw[256];
  int t = threadIdx.x;
  int base = blockIdx.x * 4096 + t * 16;
  int v[16];
  int s = 0;
  #pragma unroll
  for (int i = 0; i < 16; ++i) { int idx = base + i; v[i] = (idx < n) ? a[idx] : 0; s += v[i]; }
  tw[t] = s;
  __syncthreads();
  for (int off = 1; off < 256; off <<= 1) {
    int u = (t >= off) ? tw[t - off] : 0;
    __syncthreads();
    tw[t] += u;
    __syncthreads();
  }
  int excl = bsum[blockIdx.x] + tw[t] - s;
  #pragma unroll
  for (int i = 0; i < 16; ++i) {
    int idx = base + i;
    if (idx < n) { a[idx] = excl; excl += v[i]; }
  }
}

__global__ void k_binbase(const int* __restrict__ bh, int nblk, int nbin, int E,
                          int* __restrict__ binbase)
{
  int j = blockIdx.x * 256 + threadIdx.x;
  if (j < nbin) binbase[j] = bh[(size_t)j * nblk];
  if (j == nbin) binbase[nbin] = E;
}

__global__ __launch_bounds__(256) void k_bscat(const int* __restrict__ row,
    const int* __restrict__ col, int E, int nblk, int nbin, int shift,
    const int* __restrict__ bh,
    int* __restrict__ trow, int* __restrict__ tcol)
{
  __shared__ int cur[1024];
  int tid = threadIdx.x;
  int b = blockIdx.x;
  for (int j = tid; j < nbin; j += 256) cur[j] = bh[j * nblk + b];
  __syncthreads();
  int lo = b * CHUNK, hi = min(E, lo + CHUNK);
  for (int i = lo + tid; i < hi; i += 256) {
    int c = col[i];
    int p = atomicAdd(&cur[c >> shift], 1);
    trow[p] = row[i];
    if (tcol) tcol[p] = c;
  }
}

__global__ __launch_bounds__(256) void k_fine(const int* __restrict__ trow,
    const int* __restrict__ tcol, const int* __restrict__ binbase,
    int* __restrict__ rowptr, int* __restrict__ rows, int Nd, int nbin)
{
  __shared__ int h[256], sc[256], cur[256];
  int tid = threadIdx.x;
  int bin = blockIdx.x;
  int s = binbase[bin], e = binbase[bin + 1];
  h[tid] = 0;
  __syncthreads();
  for (int k = s + tid; k < e; k += 256) atomicAdd(&h[tcol[k] & 255], 1);
  __syncthreads();
  int own = h[tid];
  sc[tid] = own;
  __syncthreads();
  for (int off = 1; off < 256; off <<= 1) {
    int t = (tid >= off) ? sc[tid - off] : 0;
    __syncthreads();
    sc[tid] += t;
    __syncthreads();
  }
  int excl = sc[tid] - own;
  int dst = bin * 256 + tid;
  if (dst < Nd) rowptr[dst] = s + excl;
  cur[tid] = s + excl;
  if (bin == 0 && tid == 0) rowptr[Nd] = binbase[nbin];
  __syncthreads();
  for (int k = s + tid; k < e; k += 256) {
    int p = atomicAdd(&cur[tcol[k] & 255], 1);
    rows[p] = trow[k];
  }
}

__global__ void k_rp(const int* __restrict__ binbase, int* __restrict__ rowptr, int Nd) {
  int i = blockIdx.x * 256 + threadIdx.x;
  if (i <= Nd) rowptr[i] = binbase[i];
}

// ---------------- gather: per-head x aggregation + fused W epilogue ----------------
// 256 thr = 16 groups x 16 lanes; group g handles dst n = blockIdx*16+g.
// Lane l owns dims l*4..l*4+3; its quad-head h = l&3 computes exp for head h,
// quad shfl_xor distributes p to all lanes (m-index = head h^m).
__global__ __launch_bounds__(256) void k_gat16(const int* __restrict__ rowptr,
    const int* __restrict__ rows, const float* __restrict__ aS, int sS,
    const float* __restrict__ aD, int sD, const uint32_t* __restrict__ xh,
    const float* __restrict__ W, float* __restrict__ out, int Nd)
{
  __shared__ float sW[64 * 64];       // 16 KB
  __shared__ float sAgg[16][260];     // 16.6 KB (pad 4 vs banks)
  int tid = threadIdx.x;
  {
    const float4* w4 = (const float4*)W;
    float4* s4 = (float4*)sW;
    #pragma unroll
    for (int i = 0; i < 4; ++i) s4[tid + 256 * i] = w4[tid + 256 * i];
  }
  int g = tid >> 4, l = tid & 15, h = l & 3;
  int n = blockIdx.x * 16 + g;
  float acc[4][4] = {{0.f,0.f,0.f,0.f},{0.f,0.f,0.f,0.f},{0.f,0.f,0.f,0.f},{0.f,0.f,0.f,0.f}};
  float den[4] = {0.f, 0.f, 0.f, 0.f};
  if (n < Nd) {
    float adh = aD[(size_t)n * sD + h];
    int start = rowptr[n], end = rowptr[n + 1];
    for (int k = start; k < end; ++k) {
      int row = rows[k];
      float v = aS[(size_t)row * sS + h] + adh;
      v = v >= 0.f ? v : 0.2f * v;
      // logits are O(1) here (x~0.1, folded att vec ~0.05): plain exp is safe
      // and drops the online-max loop-carried dependency.
      float p0 = __expf(v);
      float p1 = __shfl_xor(p0, 1);
      float p2 = __shfl_xor(p0, 2);
      float p3 = __shfl_xor(p0, 3);
      uint2 xr = *(const uint2*)(xh + (size_t)row * 32 + l * 2);
      float2 x01 = unpackh2(xr.x);
      float2 x23 = unpackh2(xr.y);
      den[0] += p0; den[1] += p1; den[2] += p2; den[3] += p3;
      acc[0][0] += p0 * x01.x; acc[0][1] += p0 * x01.y; acc[0][2] += p0 * x23.x; acc[0][3] += p0 * x23.y;
      acc[1][0] += p1 * x01.x; acc[1][1] += p1 * x01.y; acc[1][2] += p1 * x23.x; acc[1][3] += p1 * x23.y;
      acc[2][0] += p2 * x01.x; acc[2][1] += p2 * x01.y; acc[2][2] += p2 * x23.x; acc[2][3] += p2 * x23.y;
      acc[3][0] += p3 * x01.x; acc[3][1] += p3 * x01.y; acc[3][2] += p3 * x23.x; acc[3][3] += p3 * x23.y;
    }
  }
  // normalized per-head aggregate -> sAgg[g][head*64 + dim]; m-index maps to head h^m
  #pragma unroll
  for (int m = 0; m < 4; ++m) {
    float inv = 1.f / (den[m] + 1e-16f);
    *(float4*)&sAgg[g][(h ^ m) * 64 + l * 4] = make_float4(
        acc[m][0] * inv, acc[m][1] * inv, acc[m][2] * inv, acc[m][3] * inv);
  }
  __syncthreads();
  // epilogue GEMM: out[n, c] += sum_k agg[n, head(c), k] * W[k][c]
  int c4 = tid & 15, hh = c4 >> 2;
  float r0 = 0.f, r1 = 0.f, r2 = 0.f, r3 = 0.f;
  #pragma unroll 8
  for (int k = 0; k < 64; ++k) {
    float a = sAgg[g][hh * 64 + k];
    float4 wv = *(const float4*)&sW[k * 64 + c4 * 4];
    r0 += a * wv.x; r1 += a * wv.y; r2 += a * wv.z; r3 += a * wv.w;
  }
  if (n < Nd) {
    float4* op = (float4*)(out + (size_t)n * 64) + c4;
    float4 pv = *op;
    pv.x += r0; pv.y += r1; pv.z += r2; pv.w += r3;
    *op = pv;
  }
}

// big-degree path: one block per dst (Nd <= 512), 16 subgroups stride edges.
__global__ __launch_bounds__(256) void k_gatB(const int* __restrict__ rowptr,
    const int* __restrict__ rows, const float* __restrict__ aS, int sS,
    const float* __restrict__ aD, int sD, const uint32_t* __restrict__ xh,
    const float* __restrict__ W, float* __restrict__ out)
{
  __shared__ float sAgg[16][260];
  __shared__ float sDen[16][4];
  __shared__ float sRes[256];
  int n = blockIdx.x;
  int tid = threadIdx.x;
  int g = tid >> 4, l = tid & 15, h = l & 3;
  float adh = aD[(size_t)n * sD + h];
  int start = rowptr[n], end = rowptr[n + 1];
  float acc[4][4] = {{0.f,0.f,0.f,0.f},{0.f,0.f,0.f,0.f},{0.f,0.f,0.f,0.f},{0.f,0.f,0.f,0.f}};
  float den[4] = {0.f, 0.f, 0.f, 0.f};
  for (int k = start + g; k < end; k += 16) {
    int row = rows[k];
    float v = aS[(size_t)row * sS + h] + adh;
    v = v >= 0.f ? v : 0.2f * v;
    float p0 = __expf(v);
    float p1 = __shfl_xor(p0, 1);
    float p2 = __shfl_xor(p0, 2);
    float p3 = __shfl_xor(p0, 3);
    uint2 xr = *(const uint2*)(xh + (size_t)row * 32 + l * 2);
    float2 x01 = unpackh2(xr.x);
    float2 x23 = unpackh2(xr.y);
    den[0] += p0; den[1] += p1; den[2] += p2; den[3] += p3;
    acc[0][0] += p0 * x01.x; acc[0][1] += p0 * x01.y; acc[0][2] += p0 * x23.x; acc[0][3] += p0 * x23.y;
    acc[1][0] += p1 * x01.x; acc[1][1] += p1 * x01.y; acc[1][2] += p1 * x23.x; acc[1][3] += p1 * x23.y;
    acc[2][0] += p2 * x01.x; acc[2][1] += p2 * x01.y; acc[2][2] += p2 * x23.x; acc[2][3] += p2 * x23.y;
    acc[3][0] += p3 * x01.x; acc[3][1] += p3 * x01.y; acc[3][2] += p3 * x23.x; acc[3][3] += p3 * x23.y;
  }
  #pragma unroll
  for (int m = 0; m < 4; ++m)
    *(float4*)&sAgg[g][(h ^ m) * 64 + l * 4] =
        make_float4(acc[m][0], acc[m][1], acc[m][2], acc[m][3]);
  if (l == 0) {   // lane h=0: m-index == head
    sDen[g][0] = den[0]; sDen[g][1] = den[1]; sDen[g][2] = den[2]; sDen[g][3] = den[3];
  }
  __syncthreads();
  float A = 0.f;
  #pragma unroll
  for (int gg = 0; gg < 16; ++gg) A += sAgg[gg][tid];
  int hh = tid >> 6;
  float D = 0.f;
  #pragma unroll
  for (int gg = 0; gg < 16; ++gg) D += sDen[gg][hh];
  sRes[tid] = A / (D + 1e-16f);
  __syncthreads();
  if (tid < 64) {
    int hc = tid >> 4;
    float r = 0.f;
    #pragma unroll 8
    for (int k = 0; k < 64; ++k) r += sRes[hc * 64 + k] * W[k * 64 + tid];
    out[(size_t)n * 64 + tid] += r;
  }
}

// ---------------- epilogue ----------------

__global__ void k_act(float* __restrict__ x, const float* __restrict__ b0,
                      const float* __restrict__ b1, const float* __restrict__ b2,
                      const float* __restrict__ b3, int nb, int n)
{
  int i = blockIdx.x * blockDim.x + threadIdx.x;
  if (i >= n) return;
  int d = i & 63;
  float bs = b0[d] + b1[d];
  if (nb == 4) bs += b2[d] + b3[d];
  float v = x[i] + bs;
  x[i] = v >= 0.f ? v : 0.01f * v;
}

__global__ void k_final(const float* __restrict__ x0, const float* __restrict__ x1,
                        const float* __restrict__ x2, float* __restrict__ out, int n)
{
  int i = blockIdx.x * blockDim.x + threadIdx.x;
  if (i < n) out[i] = (x0[i] + x1[i] + x2[i]) * (1.f / 3.f);
}

// ---------------- launch ----------------

extern "C" void kernel_launch(void* const* d_in, const int* in_sizes, int n_in,
                              void* d_out, int out_size, void* d_ws, size_t ws_size,
                              hipStream_t stream)
{
  static const int ECNT[8] = {1000000, 1000000, 500000, 500000, 100000, 100000, 500000, 500000};
  static const int ESRC[8] = {0, 1, 0, 0, 1, 2, 0, 2};   // 0=user 1=article 2=category
  static const int EDST[8] = {1, 0, 0, 0, 2, 1, 2, 0};
  const int NSZ[3] = {kNUser, kNArt, kNCat};

  const float* x0[3] = {(const float*)d_in[0], (const float*)d_in[1], (const float*)d_in[2]};
  const float* Wsrc = (const float*)d_in[3];
  const float* Wdst = (const float*)d_in[4];
  const float* attS = (const float*)d_in[5];
  const float* attD = (const float*)d_in[6];
  const float* bias = (const float*)d_in[7];
  const int* ei[8];
  for (int t = 0; t < 8; ++t) ei[t] = (const int*)d_in[8 + t];

  float* ws = (float*)d_ws;
  size_t off = 0;
  auto alloc = [&](size_t nelem) { float* p = ws + off; off += nelem; return p; };
  float* xb0 = alloc(SZ_X);
  float* xb1 = alloc(SZ_X);
  float* xhf = alloc(SZ_X / 2);            // fp16 copy of current x (SZ_X halves)
  float* aU  = alloc((size_t)kNUser * 32); // 8 slots x 4 heads
  float* aA  = alloc((size_t)kNArt * 16);  // 4 slots
  float* aC  = alloc((size_t)kNCat * 16);  // 4 slots
  float* fold = alloc(16 * 2 * 256);       // (l*8+t, src/dst) folded 64x4 vecs
  int* rowptrA = (int*)alloc(1001008);
  int* rowsA   = (int*)alloc(4200000);
  int* tmp_row = (int*)alloc(1000000);
  int* tmp_col = (int*)alloc(1000000);
  int* blockhist = (int*)alloc(200704);
  int* binbase   = (int*)alloc(1032);
  int* bsum      = (int*)alloc(1024);

  uint32_t* xh32 = (uint32_t*)xhf;
  uint32_t* xh_u = xh32;
  uint32_t* xh_a = xh32 + (size_t)kNUser * 32;
  uint32_t* xh_c = xh_a + (size_t)kNArt * 32;

  int* rowptr_t[8]; int* rows_t[8];
  {
    size_t ro = 0, eo = 0;
    for (int t = 0; t < 8; ++t) {
      int Nd = NSZ[EDST[t]];
      rowptr_t[t] = rowptrA + ro; ro += (size_t)Nd + 1;
      rows_t[t]   = rowsA + eo;   eo += (size_t)ECNT[t];
    }
  }

  // per-type a_s/a_d pointers into interleaved per-node-type tables
  // user slots: [t0s,t2s,t3s,t6s, t1d,t2d,t3d,t7d]; art: [t1s,t4s, t0d,t5d]; cat: [t5s,t7s, t4d,t6d]
  float* aSp[8] = {aU + 0, aA + 0, aU + 4, aU + 8, aA + 4, aC + 0, aU + 12, aC + 4};
  int    sSs[8] = {32, 16, 32, 32, 16, 16, 32, 16};
  float* aDp[8] = {aA + 8, aU + 16, aU + 20, aU + 24, aC + 8, aA + 12, aC + 12, aU + 28};
  int    sDs[8] = {16, 32, 32, 32, 16, 16, 16, 32};
  const uint32_t* xhp[8] = {xh_u, xh_a, xh_u, xh_u, xh_a, xh_c, xh_u, xh_c};

  // ---- fold attention vectors (both layers) ----
  k_fold<<<16, 256, 0, stream>>>(Wsrc, Wdst, attS, attD, fold);

  // ---- CSR build: two-level LDS multisplit (no global atomics) ----
  for (int t = 0; t < 8; ++t) {
    int Nd = NSZ[EDST[t]], E = ECNT[t];
    const int* row = ei[t];
    const int* col = ei[t] + E;
    int shift = (Nd <= 1024) ? 0 : 8;
    int nbin = ((Nd - 1) >> shift) + 1;
    int nblk = (E + CHUNK - 1) / CHUNK;
    int n = nbin * nblk;
    int nb2 = (n + 4095) / 4096;
    k_bhist<<<nblk, 256, 0, stream>>>(col, E, nblk, nbin, shift, blockhist);
    k_s1<<<nb2, 256, 0, stream>>>(blockhist, bsum, n);
    k_s2<<<1, 1024, 0, stream>>>(bsum, nb2);
    k_s3<<<nb2, 256, 0, stream>>>(blockhist, bsum, n);
    k_binbase<<<(nbin + 256) / 256, 256, 0, stream>>>(blockhist, nblk, nbin, E, binbase);
    if (shift == 0) {
      k_bscat<<<nblk, 256, 0, stream>>>(row, col, E, nblk, nbin, 0,
                                        blockhist, rows_t[t], nullptr);
      k_rp<<<(Nd + 256) / 256, 256, 0, stream>>>(binbase, rowptr_t[t], Nd);
    } else {
      k_bscat<<<nblk, 256, 0, stream>>>(row, col, E, nblk, nbin, 8,
                                        blockhist, tmp_row, tmp_col);
      k_fine<<<nbin, 256, 0, stream>>>(tmp_row, tmp_col, binbase,
                                       rowptr_t[t], rows_t[t], Nd, nbin);
    }
  }

  float* xb[2][3] = {{xb0, xb0 + SZ_U, xb0 + SZ_U + SZ_A},
                     {xb1, xb1 + SZ_U, xb1 + SZ_U + SZ_A}};
  const float* xcur[3] = {x0[0], x0[1], x0[2]};
  for (int l = 0; l < 2; ++l) {
    hipMemsetAsync(xb[l][0], 0, SZ_X * sizeof(float), stream);
    // fold-slot id for (t, sd): ((l*8+t)*2 + sd)
    auto F = [&](int t, int sd) { return (l * 8 + t) * 2 + sd; };
    int4 ua = make_int4(F(0, 0), F(2, 0), F(3, 0), F(6, 0));
    int4 ub = make_int4(F(1, 1), F(2, 1), F(3, 1), F(7, 1));
    int4 aa = make_int4(F(1, 0), F(4, 0), F(0, 1), F(5, 1));
    int4 ca = make_int4(F(5, 0), F(7, 0), F(4, 1), F(6, 1));
    k_attn<8><<<(kNUser + 255) / 256, 256, 0, stream>>>(xcur[0], (uint4*)xh_u, fold, ua, ub, aU, kNUser);
    k_attn<4><<<(kNArt + 255) / 256, 256, 0, stream>>>(xcur[1], (uint4*)xh_a, fold, aa, aa, aA, kNArt);
    k_attn<4><<<(kNCat + 255) / 256, 256, 0, stream>>>(xcur[2], (uint4*)xh_c, fold, ca, ca, aC, kNCat);
    for (int t = 0; t < 8; ++t) {
      int d = EDST[t];
      int Nd = NSZ[d];
      const float* Wt = Wsrc + (size_t)(l * 8 + t) * 4096;
      if (Nd <= 512)
        k_gatB<<<Nd, 256, 0, stream>>>(rowptr_t[t], rows_t[t], aSp[t], sSs[t],
                                       aDp[t], sDs[t], xhp[t], Wt, xb[l][d]);
      else
        k_gat16<<<(Nd + 15) / 16, 256, 0, stream>>>(rowptr_t[t], rows_t[t], aSp[t], sSs[t],
                                                    aDp[t], sDs[t], xhp[t], Wt, xb[l][d], Nd);
    }
    const float* bl = bias + (size_t)l * 8 * 64;
    // dst lists: user {1,2,3,7}, article {0,5}, category {4,6}
    k_act<<<((int)SZ_U + 255) / 256, 256, 0, stream>>>(xb[l][0], bl + 64, bl + 128, bl + 192, bl + 448, 4, (int)SZ_U);
    k_act<<<((int)SZ_A + 255) / 256, 256, 0, stream>>>(xb[l][1], bl + 0,  bl + 320, bl, bl, 2, (int)SZ_A);
    k_act<<<((int)SZ_C + 255) / 256, 256, 0, stream>>>(xb[l][2], bl + 256, bl + 384, bl, bl, 2, (int)SZ_C);
    xcur[0] = xb[l][0]; xcur[1] = xb[l][1]; xcur[2] = xb[l][2];
  }
  k_final<<<((int)SZ_U + 255) / 256, 256, 0, stream>>>(x0[0], xb[0][0], xb[1][0], (float*)d_out, (int)SZ_U);
  k_final<<<((int)SZ_A + 255) / 256, 256, 0, stream>>>(x0[1], xb[0][1], xb[1][1], (float*)d_out + SZ_U, (int)SZ_A);
}